// Round 11
// baseline (145.391 us; speedup 1.0000x reference)
//
#include <hip/hip_runtime.h>
#include <hip/hip_bf16.h>

#define SEGS   16384
#define DCH    128
#define CHUNK  64
#define SEGPB  4          // consecutive segments per block
#define FPITCH 132        // f32 plane pitch (528B rows, 16B-aligned, 2-way max)
#define XHBLK  520        // frag-layout block stride in shorts (16 blocks of 512+8 pad)
#define LOG2E  1.4426950408889634f

using f32x4  = __attribute__((ext_vector_type(4))) float;
using bf16x8 = __attribute__((ext_vector_type(8))) short;
using u32x2  = __attribute__((ext_vector_type(2))) unsigned int;
using u32x4  = __attribute__((ext_vector_type(4))) unsigned int;

__device__ __forceinline__ float u2f(unsigned int u) { return __uint_as_float(u); }
__device__ __forceinline__ unsigned int f2u(float f) { return __float_as_uint(f); }

// ---------------------------------------------------------------------------
// Setup: (a) W' = W * log2e -> fragment-ready bf16 (RTNE) B layout
//        (b) per-segment row starts via binary search on sorted index
// ---------------------------------------------------------------------------
__global__ void setup_kernel(const float* __restrict__ W,
                             const int* __restrict__ index, int N,
                             unsigned short* __restrict__ WfH,
                             int* __restrict__ seg_start) {
  int i = blockIdx.x * blockDim.x + threadIdx.x;
  if (i < DCH * DCH) {
    int n = i >> 7, k = i & 127;           // W[n][k]
    float w = W[i] * LOG2E;                // fold log2e -> raw exp2 in softmax
    unsigned int u = f2u(w);
    unsigned int r = (u + 0x7FFFu + ((u >> 16) & 1)) >> 16;  // RTNE bf16
    int kt    = k >> 5;
    int ntile = n >> 4;
    int lane  = (n & 15) + 16 * ((k >> 3) & 3);
    int j     = k & 7;
    int dst = ((kt * 8 + ntile) * 64 + lane) * 8 + j;
    WfH[dst] = (unsigned short)r;
  } else if (i < DCH * DCH + SEGS + 1) {
    int s = i - DCH * DCH;                 // lower_bound(index, s)
    int lo = 0, hi = N;
    while (lo < hi) {
      int mid = (lo + hi) >> 1;
      if (index[mid] < s) lo = mid + 1; else hi = mid;
    }
    seg_start[s] = lo;
  }
}

// ---------------------------------------------------------------------------
// Main: block b owns segments [4b, 4b+4). 4 waves; wave w owns channels
// [32w, 32w+32). CHUNK=64: one chunk covers a typical segment (mean len 61),
// halving barriers / bookkeeping / pv-stall exposures vs CHUNK=32, with 8
// dwordx4 loads in flight per wave. Single-buffered LDS, 2 raw barriers per
// chunk; prefetched global loads stay in flight across both (no vmcnt drain).
// LDS: xh = x_hi bf16 in MFMA-fragment layout [kt][rowtile][lane][8] (+pad):
//      staging writes b64 @ imm offsets; frag reads dense b128 at lane*16+imm.
//      xf = exact f32 x plane for the e*x accumulation.
// ---------------------------------------------------------------------------
__global__ __launch_bounds__(256) void pool_kernel(
    const float* __restrict__ x, const float* __restrict__ bias,
    const int* __restrict__ seg_start,
    const u32x4* __restrict__ WfH,
    float* __restrict__ out) {
  __shared__ unsigned short xh[16 * XHBLK];     // 16.6 KB
  __shared__ float          xf[CHUNK * FPITCH]; // 33.8 KB

  const int t    = threadIdx.x;
  const int wv   = t >> 6;
  const int lane = t & 63;
  const int cl   = lane & 15;              // C col within 16-tile (channel)
  const int g    = lane >> 4;              // lane group (k-slice / row group)
  const int k31  = t & 31;                 // staging lane-in-phase
  const int lrow = t >> 5;                 // staging rows 0..7 (+8 per p)
  const int lcol = k31 << 2;               // staging col (4 floats)

  // staging bases (constant per thread); 4 xh-blocks per kt now
  const int xh_base = 2080 * (k31 >> 3) + 8 * lrow + 128 * ((k31 >> 1) & 3) + 4 * (k31 & 1);
  const int xf_base = lrow * FPITCH + lcol;
  // compute-phase bases
  const int frag_base = lane * 8;                    // shorts
  const int ex_base   = g * 4 * FPITCH + wv * 32 + cl;

  // Register-resident W fragments (this wave's 32 channels).
  u32x4 bh[4][2];
#pragma unroll
  for (int kt = 0; kt < 4; ++kt)
#pragma unroll
    for (int nt = 0; nt < 2; ++nt) {
      int off = (kt * 8 + (wv * 2 + nt)) * 64 + lane;   // 16B units
      bh[kt][nt] = WfH[off];
    }

  const float bc0 = bias[wv * 32 + cl]      * LOG2E;
  const float bc1 = bias[wv * 32 + 16 + cl] * LOG2E;

  const int s0   = blockIdx.x * SEGPB;
  const int sEnd = s0 + SEGPB;

  // Empty segments (rare): write zeros outside the pipeline, keep CF uniform.
  for (int es = s0; es < sEnd; ++es) {
    if (seg_start[es + 1] == seg_start[es] && lane < 16) {
      out[(size_t)es * DCH + wv * 32 + cl]      = 0.f;
      out[(size_t)es * DCH + wv * 32 + 16 + cl] = 0.f;
    }
  }

  int s = s0;
  while (s < sEnd && seg_start[s + 1] == seg_start[s]) ++s;
  if (s >= sEnd) return;                   // whole block empty (uniform exit)

  int c0  = 0;
  int len = seg_start[s + 1] - seg_start[s];
  int cnt = (len < CHUNK) ? len : CHUNK;

  // Prefetch first chunk into registers (rows >= cnt zero-filled).
  f32x4 pv[8];
  {
    const int base = seg_start[s];
#pragma unroll
    for (int p = 0; p < 8; ++p) {
      int lr = lrow + p * 8;
      f32x4 v = {0.f, 0.f, 0.f, 0.f};
      if (lr < cnt) v = *(const f32x4*)(x + (size_t)(base + lr) * DCH + lcol);
      pv[p] = v;
    }
  }

  float den[2] = {0.f, 0.f};
  float num[2] = {0.f, 0.f};

  while (true) {
    // ---- next-chunk coordinates (wave-uniform scalar work) ----
    int ns = s, nc0 = c0 + CHUNK;
    if (nc0 >= len) {
      nc0 = 0; ns = s + 1;
      while (ns < sEnd && seg_start[ns + 1] == seg_start[ns]) ++ns;
    }
    const bool have_next = (ns < sEnd);
    int nlen = 0, ncnt = 0, nbase = 0;
    if (have_next) {
      nbase = seg_start[ns] + nc0;
      nlen  = seg_start[ns + 1] - seg_start[ns];
      ncnt  = nlen - nc0; if (ncnt > CHUNK) ncnt = CHUNK;
    }

    // ---- PHASE W: convert pv -> xh (frag layout) + xf (f32 plane) ----
#pragma unroll
    for (int p = 0; p < 8; ++p) {
      f32x4 v = pv[p];
      unsigned int u0 = f2u(v[0]), u1 = f2u(v[1]), u2 = f2u(v[2]), u3 = f2u(v[3]);
      u32x2 H = { (u1 & 0xFFFF0000u) | (u0 >> 16),
                  (u3 & 0xFFFF0000u) | (u2 >> 16) };
      *(u32x2*)&xh[xh_base + (p >> 1) * XHBLK + (p & 1) * 64] = H;
      *(f32x4*)&xf[xf_base + p * 8 * FPITCH] = v;
    }

    // ---- issue next chunk's global loads (in flight through both barriers) --
    if (have_next) {
#pragma unroll
      for (int p = 0; p < 8; ++p) {
        int lr = lrow + p * 8;
        f32x4 v = {0.f, 0.f, 0.f, 0.f};
        if (lr < ncnt) v = *(const f32x4*)(x + (size_t)(nbase + lr) * DCH + lcol);
        pv[p] = v;
      }
    }

    // ---- barrier A: LDS writes visible; prefetch NOT drained ----
    asm volatile("s_waitcnt lgkmcnt(0)" ::: "memory");
    __builtin_amdgcn_sched_barrier(0);
    __builtin_amdgcn_s_barrier();
    __builtin_amdgcn_sched_barrier(0);

    // ---- PHASE R: att' = x @ W'^T + b' (this wave's 32 channels) ----
    f32x4 Cf[4][2];
#pragma unroll
    for (int mt = 0; mt < 4; ++mt) {
      Cf[mt][0] = (f32x4){bc0, bc0, bc0, bc0};
      Cf[mt][1] = (f32x4){bc1, bc1, bc1, bc1};
    }

#pragma unroll
    for (int kt = 0; kt < 4; ++kt) {
      u32x4 ah[4];
#pragma unroll
      for (int mt = 0; mt < 4; ++mt)
        ah[mt] = *(const u32x4*)&xh[frag_base + (4 * kt + mt) * XHBLK];
#pragma unroll
      for (int mt = 0; mt < 4; ++mt)
#pragma unroll
        for (int nt = 0; nt < 2; ++nt) {
          bf16x8 A = __builtin_bit_cast(bf16x8, ah[mt]);
          bf16x8 B = __builtin_bit_cast(bf16x8, bh[kt][nt]);
          Cf[mt][nt] = __builtin_amdgcn_mfma_f32_16x16x32_bf16(A, B, Cf[mt][nt], 0, 0, 0);
        }
    }

    // ---- e = exp2(att'); e*x from exact f32 plane ----
    // C layout: col = lane&15 (channel), row(in 16-tile) = g*4 + reg  [m89/m91]
#pragma unroll
    for (int nt = 0; nt < 2; ++nt) {
#pragma unroll
      for (int mt = 0; mt < 4; ++mt)
#pragma unroll
        for (int r = 0; r < 4; ++r) {
          const int row = mt * 16 + g * 4 + r;
          float p = __builtin_amdgcn_exp2f(Cf[mt][nt][r]);
          p = (row < cnt) ? p : 0.f;
          float xv = xf[ex_base + (mt * 16 + r) * FPITCH + nt * 16];
          den[nt] += p;
          num[nt] += p * xv;
        }
    }

    // ---- segment bookkeeping ----
    if (c0 + CHUNK >= len) {               // segment s complete -> store
#pragma unroll
      for (int nt = 0; nt < 2; ++nt) {
        float l = den[nt], a = num[nt];
        l += __shfl_xor(l, 16); l += __shfl_xor(l, 32);
        a += __shfl_xor(a, 16); a += __shfl_xor(a, 32);
        if (lane < 16)
          out[(size_t)s * DCH + wv * 32 + nt * 16 + cl] = a / (l + 1e-16f);
        den[nt] = 0.f; num[nt] = 0.f;
      }
      if (!have_next) break;
      s = ns; len = nlen; c0 = 0;
    } else {
      c0 = nc0;
    }
    cnt = ncnt;

    // ---- barrier B: all reads of this chunk done -> buffer reusable ----
    asm volatile("s_waitcnt lgkmcnt(0)" ::: "memory");
    __builtin_amdgcn_sched_barrier(0);
    __builtin_amdgcn_s_barrier();
    __builtin_amdgcn_sched_barrier(0);
  }
}

extern "C" void kernel_launch(void* const* d_in, const int* in_sizes, int n_in,
                              void* d_out, int out_size, void* d_ws, size_t ws_size,
                              hipStream_t stream) {
  const float* x    = (const float*)d_in[0];
  const float* W    = (const float*)d_in[1];
  const float* bias = (const float*)d_in[2];
  const int*   idx  = (const int*)d_in[3];
  const int N = in_sizes[0] / DCH;

  unsigned short* WfH = (unsigned short*)d_ws;            // 32 KB
  int* seg = (int*)(WfH + DCH * DCH);                     // (SEGS+1)*4 B

  int setup_threads = DCH * DCH + SEGS + 1;
  setup_kernel<<<(setup_threads + 255) / 256, 256, 0, stream>>>(W, idx, N, WfH, seg);
  pool_kernel<<<SEGS / SEGPB, 256, 0, stream>>>(x, bias, seg,
                                                (const u32x4*)WfH,
                                                (float*)d_out);
}

// Round 12
// 129.854 us; speedup vs baseline: 1.1197x; 1.1197x over previous
//
#include <hip/hip_runtime.h>
#include <hip/hip_bf16.h>

#define SEGS   16384
#define DCH    128
#define CHUNK  32
#define SEGPB  8          // consecutive segments per block
#define FPITCH 132        // f32 plane pitch (528B rows, 16B-aligned, 2-way max)
#define XHBLK  520        // frag-layout block stride in shorts (8 blocks of 512+8 pad)
#define LOG2E  1.4426950408889634f

using f32x4  = __attribute__((ext_vector_type(4))) float;
using bf16x8 = __attribute__((ext_vector_type(8))) short;
using u32x2  = __attribute__((ext_vector_type(2))) unsigned int;
using u32x4  = __attribute__((ext_vector_type(4))) unsigned int;

__device__ __forceinline__ float u2f(unsigned int u) { return __uint_as_float(u); }
__device__ __forceinline__ unsigned int f2u(float f) { return __float_as_uint(f); }

// ---------------------------------------------------------------------------
// Setup: (a) W' = W * log2e -> fragment-ready bf16 (RTNE) B layout
//        (b) per-segment row starts via binary search on sorted index
// ---------------------------------------------------------------------------
__global__ void setup_kernel(const float* __restrict__ W,
                             const int* __restrict__ index, int N,
                             unsigned short* __restrict__ WfH,
                             int* __restrict__ seg_start) {
  int i = blockIdx.x * blockDim.x + threadIdx.x;
  if (i < DCH * DCH) {
    int n = i >> 7, k = i & 127;           // W[n][k]
    float w = W[i] * LOG2E;                // fold log2e -> raw exp2 in softmax
    unsigned int u = f2u(w);
    unsigned int r = (u + 0x7FFFu + ((u >> 16) & 1)) >> 16;  // RTNE bf16
    int kt    = k >> 5;
    int ntile = n >> 4;
    int lane  = (n & 15) + 16 * ((k >> 3) & 3);
    int j     = k & 7;
    int dst = ((kt * 8 + ntile) * 64 + lane) * 8 + j;
    WfH[dst] = (unsigned short)r;
  } else if (i < DCH * DCH + SEGS + 1) {
    int s = i - DCH * DCH;                 // lower_bound(index, s)
    int lo = 0, hi = N;
    while (lo < hi) {
      int mid = (lo + hi) >> 1;
      if (index[mid] < s) lo = mid + 1; else hi = mid;
    }
    seg_start[s] = lo;
  }
}

// ---------------------------------------------------------------------------
// Main: block b owns segments [8b, 8b+8). 4 waves; wave w owns channels
// [32w, 32w+32). R10 structure (single-buffer LDS, 2 raw barriers/chunk,
// frag-layout xh + exact f32 xf) + DEPTH-2 register prefetch: chunk c+2's
// global loads are issued at chunk c via ping-ponged pvA/pvB (statically
// named, 2-unrolled body), so HBM latency is covered by ~2 full chunk
// iterations. Prefetched loads cross both barriers un-drained (no vmcnt).
// ---------------------------------------------------------------------------
__global__ __launch_bounds__(256) void pool_kernel(
    const float* __restrict__ x, const float* __restrict__ bias,
    const int* __restrict__ seg_start,
    const u32x4* __restrict__ WfH,
    float* __restrict__ out) {
  __shared__ unsigned short xh[8 * XHBLK];      // 8.32 KB
  __shared__ float          xf[CHUNK * FPITCH]; // 16.9 KB

  const int t    = threadIdx.x;
  const int wv   = t >> 6;
  const int lane = t & 63;
  const int cl   = lane & 15;              // C col within 16-tile (channel)
  const int g    = lane >> 4;              // lane group (k-slice / row group)
  const int k31  = t & 31;                 // staging lane-in-phase
  const int lrow = t >> 5;                 // staging rows 0..7 (+8 per p)
  const int lcol = k31 << 2;               // staging col (4 floats)

  const int xh_base = 1040 * (k31 >> 3) + 8 * lrow + 128 * ((k31 >> 1) & 3) + 4 * (k31 & 1);
  const int xf_base = lrow * FPITCH + lcol;
  const int frag_base = lane * 8;                    // shorts
  const int ex_base   = g * 4 * FPITCH + wv * 32 + cl;

  // Register-resident W fragments (this wave's 32 channels).
  u32x4 bh[4][2];
#pragma unroll
  for (int kt = 0; kt < 4; ++kt)
#pragma unroll
    for (int nt = 0; nt < 2; ++nt) {
      int off = (kt * 8 + (wv * 2 + nt)) * 64 + lane;   // 16B units
      bh[kt][nt] = WfH[off];
    }

  const float bc0 = bias[wv * 32 + cl]      * LOG2E;
  const float bc1 = bias[wv * 32 + 16 + cl] * LOG2E;

  const int s0   = blockIdx.x * SEGPB;
  const int sEnd = s0 + SEGPB;

  // Empty segments (rare): write zeros outside the pipeline, keep CF uniform.
  for (int es = s0; es < sEnd; ++es) {
    if (seg_start[es + 1] == seg_start[es] && lane < 16) {
      out[(size_t)es * DCH + wv * 32 + cl]      = 0.f;
      out[(size_t)es * DCH + wv * 32 + 16 + cl] = 0.f;
    }
  }

  int s = s0;
  while (s < sEnd && seg_start[s + 1] == seg_start[s]) ++s;
  if (s >= sEnd) return;                   // whole block empty (uniform exit)

  // ---- chunk metadata (all wave- and block-uniform) ----
  int curS = s, curC0 = 0;
  int curLen = seg_start[s + 1] - seg_start[s];
  int curCnt = (curLen < CHUNK) ? curLen : CHUNK;

  f32x4 pvA[4], pvB[4];

  auto issue = [&](f32x4 (&pv)[4], int base, int cnt) {
#pragma unroll
    for (int p = 0; p < 4; ++p) {
      int lr = lrow + p * 8;
      f32x4 v = {0.f, 0.f, 0.f, 0.f};
      if (lr < cnt) v = *(const f32x4*)(x + (size_t)(base + lr) * DCH + lcol);
      pv[p] = v;
    }
  };

  issue(pvA, seg_start[s], curCnt);        // chunk 0 in flight ASAP

  // advance(): produce the chunk after (fs,fc0,flen); returns validity
  auto adv = [&](int fs, int fc0, int flen,
                 int &os, int &oc0, int &olen, int &ocnt, int &obase) -> bool {
    int ns = fs, nc = fc0 + CHUNK;
    if (nc >= flen) {
      nc = 0; ns = fs + 1;
      while (ns < sEnd && seg_start[ns + 1] == seg_start[ns]) ++ns;
    }
    if (ns >= sEnd) return false;
    int st = seg_start[ns];
    os = ns; oc0 = nc; olen = seg_start[ns + 1] - st;
    ocnt = olen - nc; if (ocnt > CHUNK) ocnt = CHUNK;
    obase = st + nc;
    return true;
  };

  int nxtS = 0, nxtC0 = 0, nxtLen = 0, nxtCnt = 0, nxtBase = 0;
  bool nxtV = adv(curS, curC0, curLen, nxtS, nxtC0, nxtLen, nxtCnt, nxtBase);
  if (nxtV) issue(pvB, nxtBase, nxtCnt);   // chunk 1 in flight

  float den[2] = {0.f, 0.f};
  float num[2] = {0.f, 0.f};

  // One pipeline step: stage pvS (chunk c), refill pvS with chunk c+2,
  // compute chunk c. pvL holds chunk c+1 (in flight / ready).
  auto body = [&](f32x4 (&pvS)[4], f32x4 (&pvL)[4]) -> bool {
    (void)pvL;
    // ---- PHASE W: convert pvS -> xh (frag layout) + xf (f32 plane) ----
#pragma unroll
    for (int p = 0; p < 4; ++p) {
      f32x4 v = pvS[p];
      unsigned int u0 = f2u(v[0]), u1 = f2u(v[1]), u2 = f2u(v[2]), u3 = f2u(v[3]);
      u32x2 H = { (u1 & 0xFFFF0000u) | (u0 >> 16),
                  (u3 & 0xFFFF0000u) | (u2 >> 16) };
      *(u32x2*)&xh[xh_base + (p >> 1) * XHBLK + (p & 1) * 64] = H;
      *(f32x4*)&xf[xf_base + p * 8 * FPITCH] = v;
    }

    // ---- lookahead chunk c+2, issue into pvS (regs just freed) ----
    int nnS = 0, nnC0 = 0, nnLen = 0, nnCnt = 0, nnBase = 0;
    bool nnV = false;
    if (nxtV) {
      nnV = adv(nxtS, nxtC0, nxtLen, nnS, nnC0, nnLen, nnCnt, nnBase);
      if (nnV) issue(pvS, nnBase, nnCnt);
    }

    // ---- barrier A: LDS writes visible; prefetches NOT drained ----
    asm volatile("s_waitcnt lgkmcnt(0)" ::: "memory");
    __builtin_amdgcn_sched_barrier(0);
    __builtin_amdgcn_s_barrier();
    __builtin_amdgcn_sched_barrier(0);

    // ---- PHASE R: att' = x @ W'^T + b' (this wave's 32 channels) ----
    f32x4 Cf[2][2];
#pragma unroll
    for (int mt = 0; mt < 2; ++mt) {
      Cf[mt][0] = (f32x4){bc0, bc0, bc0, bc0};
      Cf[mt][1] = (f32x4){bc1, bc1, bc1, bc1};
    }
#pragma unroll
    for (int kt = 0; kt < 4; ++kt) {
      u32x4 ah[2];
#pragma unroll
      for (int mt = 0; mt < 2; ++mt)
        ah[mt] = *(const u32x4*)&xh[frag_base + (2 * kt + mt) * XHBLK];
#pragma unroll
      for (int mt = 0; mt < 2; ++mt)
#pragma unroll
        for (int nt = 0; nt < 2; ++nt) {
          bf16x8 A = __builtin_bit_cast(bf16x8, ah[mt]);
          bf16x8 B = __builtin_bit_cast(bf16x8, bh[kt][nt]);
          Cf[mt][nt] = __builtin_amdgcn_mfma_f32_16x16x32_bf16(A, B, Cf[mt][nt], 0, 0, 0);
        }
    }

    // ---- e = exp2(att'); e*x from exact f32 plane ----
    // C layout: col = lane&15 (channel), row(in 16-tile) = g*4 + reg [m89/m91]
#pragma unroll
    for (int nt = 0; nt < 2; ++nt) {
#pragma unroll
      for (int mt = 0; mt < 2; ++mt)
#pragma unroll
        for (int r = 0; r < 4; ++r) {
          const int row = mt * 16 + g * 4 + r;
          float p = __builtin_amdgcn_exp2f(Cf[mt][nt][r]);
          p = (row < curCnt) ? p : 0.f;
          float xv = xf[ex_base + (mt * 16 + r) * FPITCH + nt * 16];
          den[nt] += p;
          num[nt] += p * xv;
        }
    }

    // ---- segment bookkeeping ----
    if (curC0 + CHUNK >= curLen) {         // segment complete -> store
#pragma unroll
      for (int nt = 0; nt < 2; ++nt) {
        float l = den[nt], a = num[nt];
        l += __shfl_xor(l, 16); l += __shfl_xor(l, 32);
        a += __shfl_xor(a, 16); a += __shfl_xor(a, 32);
        if (lane < 16)
          out[(size_t)curS * DCH + wv * 32 + nt * 16 + cl] = a / (l + 1e-16f);
        den[nt] = 0.f; num[nt] = 0.f;
      }
    }
    if (!nxtV) return false;
    curS = nxtS; curC0 = nxtC0; curLen = nxtLen; curCnt = nxtCnt;
    nxtS = nnS; nxtC0 = nnC0; nxtLen = nnLen; nxtCnt = nnCnt; nxtBase = nnBase;
    nxtV = nnV;

    // ---- barrier B: all reads of this chunk done -> buffer reusable ----
    asm volatile("s_waitcnt lgkmcnt(0)" ::: "memory");
    __builtin_amdgcn_sched_barrier(0);
    __builtin_amdgcn_s_barrier();
    __builtin_amdgcn_sched_barrier(0);
    return true;
  };

  for (;;) {
    if (!body(pvA, pvB)) break;            // even chunks stage pvA
    if (!body(pvB, pvA)) break;            // odd chunks stage pvB
  }
}

extern "C" void kernel_launch(void* const* d_in, const int* in_sizes, int n_in,
                              void* d_out, int out_size, void* d_ws, size_t ws_size,
                              hipStream_t stream) {
  const float* x    = (const float*)d_in[0];
  const float* W    = (const float*)d_in[1];
  const float* bias = (const float*)d_in[2];
  const int*   idx  = (const int*)d_in[3];
  const int N = in_sizes[0] / DCH;

  unsigned short* WfH = (unsigned short*)d_ws;            // 32 KB
  int* seg = (int*)(WfH + DCH * DCH);                     // (SEGS+1)*4 B

  int setup_threads = DCH * DCH + SEGS + 1;
  setup_kernel<<<(setup_threads + 255) / 256, 256, 0, stream>>>(W, idx, N, WfH, seg);
  pool_kernel<<<SEGS / SEGPB, 256, 0, stream>>>(x, bias, seg,
                                                (const u32x4*)WfH,
                                                (float*)d_out);
}

// Round 13
// 119.311 us; speedup vs baseline: 1.2186x; 1.0884x over previous
//
#include <hip/hip_runtime.h>
#include <hip/hip_bf16.h>

#define SEGS   16384
#define DCH    128
#define CHUNK  32
#define SEGPB  4          // consecutive segments per block
#define FPITCH 132        // f32 plane pitch (528B rows, 16B-aligned, 2-way max)
#define XHBLK  520        // frag-layout block stride in shorts (8 blocks of 512+8 pad)
#define LOG2E  1.4426950408889634f

using f32x4  = __attribute__((ext_vector_type(4))) float;
using bf16x8 = __attribute__((ext_vector_type(8))) short;
using u32x2  = __attribute__((ext_vector_type(2))) unsigned int;
using u32x4  = __attribute__((ext_vector_type(4))) unsigned int;

__device__ __forceinline__ float u2f(unsigned int u) { return __uint_as_float(u); }
__device__ __forceinline__ unsigned int f2u(float f) { return __float_as_uint(f); }

// ---------------------------------------------------------------------------
// Setup: (a) W' = W * log2e -> fragment-ready bf16 (RTNE) B layout
//        (b) per-segment row starts via binary search on sorted index
// ---------------------------------------------------------------------------
__global__ void setup_kernel(const float* __restrict__ W,
                             const int* __restrict__ index, int N,
                             unsigned short* __restrict__ WfH,
                             int* __restrict__ seg_start) {
  int i = blockIdx.x * blockDim.x + threadIdx.x;
  if (i < DCH * DCH) {
    int n = i >> 7, k = i & 127;           // W[n][k]
    float w = W[i] * LOG2E;                // fold log2e -> raw exp2 in softmax
    unsigned int u = f2u(w);
    unsigned int r = (u + 0x7FFFu + ((u >> 16) & 1)) >> 16;  // RTNE bf16
    int kt    = k >> 5;
    int ntile = n >> 4;
    int lane  = (n & 15) + 16 * ((k >> 3) & 3);
    int j     = k & 7;
    int dst = ((kt * 8 + ntile) * 64 + lane) * 8 + j;
    WfH[dst] = (unsigned short)r;
  } else if (i < DCH * DCH + SEGS + 1) {
    int s = i - DCH * DCH;                 // lower_bound(index, s)
    int lo = 0, hi = N;
    while (lo < hi) {
      int mid = (lo + hi) >> 1;
      if (index[mid] < s) lo = mid + 1; else hi = mid;
    }
    seg_start[s] = lo;
  }
}

// ---------------------------------------------------------------------------
// Main: block b owns segments [4b, 4b+4) = contiguous rows [R0, R1).
// STREAMING CHUNKS: rows are processed in full 32-row chunks that may cross
// segment boundaries; a block-uniform sweep resolves boundaries with masked
// accumulation and flushes (shfl-reduce + store) when a segment ends inside
// the chunk. Empty segments flush zero accumulators naturally.
// R10 LDS subsystem: xh = x_hi bf16 in MFMA-fragment layout (staging b64 @
// imm, frag reads dense b128 at lane*16+imm); xf = exact f32 plane for e*x.
// Single-buffered, 2 raw barriers/chunk; depth-1 register prefetch stays in
// flight across both barriers (no vmcnt drain).
// ---------------------------------------------------------------------------
__global__ __launch_bounds__(256) void pool_kernel(
    const float* __restrict__ x, const float* __restrict__ bias,
    const int* __restrict__ seg_start,
    const u32x4* __restrict__ WfH,
    float* __restrict__ out) {
  __shared__ unsigned short xh[8 * XHBLK];      // 8.32 KB
  __shared__ float          xf[CHUNK * FPITCH]; // 16.9 KB

  const int t    = threadIdx.x;
  const int wv   = t >> 6;
  const int lane = t & 63;
  const int cl   = lane & 15;              // C col within 16-tile (channel)
  const int g    = lane >> 4;              // lane group (k-slice / row group)
  const int k31  = t & 31;                 // staging lane-in-phase
  const int lrow = t >> 5;                 // staging rows 0..7 (+8 per p)
  const int lcol = k31 << 2;               // staging col (4 floats)

  const int xh_base = 1040 * (k31 >> 3) + 8 * lrow + 128 * ((k31 >> 1) & 3) + 4 * (k31 & 1);
  const int xf_base = lrow * FPITCH + lcol;
  const int frag_base = lane * 8;                    // shorts
  const int ex_base   = g * 4 * FPITCH + wv * 32 + cl;

  // Register-resident W fragments (this wave's 32 channels).
  u32x4 bh[4][2];
#pragma unroll
  for (int kt = 0; kt < 4; ++kt)
#pragma unroll
    for (int nt = 0; nt < 2; ++nt) {
      int off = (kt * 8 + (wv * 2 + nt)) * 64 + lane;   // 16B units
      bh[kt][nt] = WfH[off];
    }

  const float bc0 = bias[wv * 32 + cl]      * LOG2E;
  const float bc1 = bias[wv * 32 + 16 + cl] * LOG2E;

  const int s0   = blockIdx.x * SEGPB;
  const int sEnd = s0 + SEGPB;
  const int R0   = seg_start[s0];
  const int R1   = seg_start[sEnd];

  if (R0 == R1) {                          // whole block empty -> zeros
    if (lane < 16) {
      for (int es = s0; es < sEnd; ++es) {
        out[(size_t)es * DCH + wv * 32 + cl]      = 0.f;
        out[(size_t)es * DCH + wv * 32 + 16 + cl] = 0.f;
      }
    }
    return;
  }

  int curSeg = s0;
  int segEnd = seg_start[curSeg + 1];

  int c0 = R0;
  // Prefetch first chunk (rows >= R1 zero-filled).
  f32x4 pv[4];
#pragma unroll
  for (int p = 0; p < 4; ++p) {
    int lr = c0 + lrow + p * 8;
    f32x4 v = {0.f, 0.f, 0.f, 0.f};
    if (lr < R1) v = *(const f32x4*)(x + (size_t)lr * DCH + lcol);
    pv[p] = v;
  }

  float den[2] = {0.f, 0.f};
  float num[2] = {0.f, 0.f};

  while (true) {
    // ---- PHASE W: convert pv -> xh (frag layout) + xf (f32 plane) ----
#pragma unroll
    for (int p = 0; p < 4; ++p) {
      f32x4 v = pv[p];
      unsigned int u0 = f2u(v[0]), u1 = f2u(v[1]), u2 = f2u(v[2]), u3 = f2u(v[3]);
      u32x2 H = { (u1 & 0xFFFF0000u) | (u0 >> 16),
                  (u3 & 0xFFFF0000u) | (u2 >> 16) };
      *(u32x2*)&xh[xh_base + (p >> 1) * XHBLK + (p & 1) * 64] = H;
      *(f32x4*)&xf[xf_base + p * 8 * FPITCH] = v;
    }

    // ---- issue next chunk's loads (linear stream; cross both barriers) ----
    const int nc0 = c0 + CHUNK;
    if (nc0 < R1) {
#pragma unroll
      for (int p = 0; p < 4; ++p) {
        int lr = nc0 + lrow + p * 8;
        f32x4 v = {0.f, 0.f, 0.f, 0.f};
        if (lr < R1) v = *(const f32x4*)(x + (size_t)lr * DCH + lcol);
        pv[p] = v;
      }
    }

    // ---- barrier A: LDS writes visible; prefetch NOT drained ----
    asm volatile("s_waitcnt lgkmcnt(0)" ::: "memory");
    __builtin_amdgcn_sched_barrier(0);
    __builtin_amdgcn_s_barrier();
    __builtin_amdgcn_sched_barrier(0);

    // ---- PHASE R: att' = x @ W'^T + b' (this wave's 32 channels) ----
    f32x4 Cf[2][2];
#pragma unroll
    for (int mt = 0; mt < 2; ++mt) {
      Cf[mt][0] = (f32x4){bc0, bc0, bc0, bc0};
      Cf[mt][1] = (f32x4){bc1, bc1, bc1, bc1};
    }
#pragma unroll
    for (int kt = 0; kt < 4; ++kt) {
      u32x4 ah[2];
#pragma unroll
      for (int mt = 0; mt < 2; ++mt)
        ah[mt] = *(const u32x4*)&xh[frag_base + (2 * kt + mt) * XHBLK];
#pragma unroll
      for (int mt = 0; mt < 2; ++mt)
#pragma unroll
        for (int nt = 0; nt < 2; ++nt) {
          bf16x8 A = __builtin_bit_cast(bf16x8, ah[mt]);
          bf16x8 B = __builtin_bit_cast(bf16x8, bh[kt][nt]);
          Cf[mt][nt] = __builtin_amdgcn_mfma_f32_16x16x32_bf16(A, B, Cf[mt][nt], 0, 0, 0);
        }
    }

    // ---- p = exp2(att'), xv from f32 plane (once per chunk) ----
    // C layout: col = lane&15 (channel), row(in 16-tile) = g*4 + reg [m89/m91]
    float pr[2][2][4], xv[2][2][4];
#pragma unroll
    for (int nt = 0; nt < 2; ++nt)
#pragma unroll
      for (int mt = 0; mt < 2; ++mt)
#pragma unroll
        for (int r = 0; r < 4; ++r) {
          pr[nt][mt][r] = __builtin_amdgcn_exp2f(Cf[mt][nt][r]);
          xv[nt][mt][r] = xf[ex_base + (mt * 16 + r) * FPITCH + nt * 16];
        }

    // ---- segment sweep (block-uniform control flow) ----
    const int lim = c0 + CHUNK;
    int lo = c0;
    while (curSeg < sEnd) {
      const int hi  = segEnd;
      const int hiC = (hi < lim) ? hi : lim;
#pragma unroll
      for (int nt = 0; nt < 2; ++nt)
#pragma unroll
        for (int mt = 0; mt < 2; ++mt)
#pragma unroll
          for (int r = 0; r < 4; ++r) {
            const int row = c0 + mt * 16 + g * 4 + r;
            const bool use = (row >= lo) & (row < hiC);
            const float pp = use ? pr[nt][mt][r] : 0.f;
            den[nt] += pp;
            num[nt] += pp * xv[nt][mt][r];
          }
      if (hi <= lim) {                     // segment ends in this chunk: flush
#pragma unroll
        for (int nt = 0; nt < 2; ++nt) {
          float l = den[nt], a = num[nt];
          l += __shfl_xor(l, 16); l += __shfl_xor(l, 32);
          a += __shfl_xor(a, 16); a += __shfl_xor(a, 32);
          if (lane < 16)
            out[(size_t)curSeg * DCH + wv * 32 + nt * 16 + cl] = a / (l + 1e-16f);
          den[nt] = 0.f; num[nt] = 0.f;
        }
        lo = hi;
        ++curSeg;
        if (curSeg < sEnd) segEnd = seg_start[curSeg + 1];
      } else {
        break;                             // segment continues into next chunk
      }
    }
    if (curSeg >= sEnd) break;             // all segments flushed -> done
    c0 = nc0;

    // ---- barrier B: all reads of this chunk done -> buffer reusable ----
    asm volatile("s_waitcnt lgkmcnt(0)" ::: "memory");
    __builtin_amdgcn_sched_barrier(0);
    __builtin_amdgcn_s_barrier();
    __builtin_amdgcn_sched_barrier(0);
  }
}

extern "C" void kernel_launch(void* const* d_in, const int* in_sizes, int n_in,
                              void* d_out, int out_size, void* d_ws, size_t ws_size,
                              hipStream_t stream) {
  const float* x    = (const float*)d_in[0];
  const float* W    = (const float*)d_in[1];
  const float* bias = (const float*)d_in[2];
  const int*   idx  = (const int*)d_in[3];
  const int N = in_sizes[0] / DCH;

  unsigned short* WfH = (unsigned short*)d_ws;            // 32 KB
  int* seg = (int*)(WfH + DCH * DCH);                     // (SEGS+1)*4 B

  int setup_threads = DCH * DCH + SEGS + 1;
  setup_kernel<<<(setup_threads + 255) / 256, 256, 0, stream>>>(W, idx, N, WfH, seg);
  pool_kernel<<<SEGS / SEGPB, 256, 0, stream>>>(x, bias, seg,
                                                (const u32x4*)WfH,
                                                (float*)d_out);
}